// Round 1
// baseline (465.670 us; speedup 1.0000x reference)
//
#include <hip/hip_runtime.h>
#include <hip/hip_bf16.h>
#include <stdint.h>

#define N_ 4096
#define H_ 1024
#define V_ 16384

using i32x8  = __attribute__((ext_vector_type(8))) int;
using f32x16 = __attribute__((ext_vector_type(16))) float;

// 8 floats -> 8 fp8 e4m3 (OCP) per thread; both tensors in one launch
__global__ void cast2_f32_to_fp8(const float* __restrict__ in0, uint8_t* __restrict__ out0,
                                 const float* __restrict__ in1, uint8_t* __restrict__ out1,
                                 int nblk0) {
    const float* in;
    uint8_t* out;
    int bid;
    if (blockIdx.x < (unsigned)nblk0) { in = in0; out = out0; bid = blockIdx.x; }
    else                              { in = in1; out = out1; bid = blockIdx.x - nblk0; }
    size_t i = ((size_t)bid * blockDim.x + threadIdx.x) * 8;
    float4 a = *(const float4*)(in + i);
    float4 b = *(const float4*)(in + i + 4);
    int lo = __builtin_amdgcn_cvt_pk_fp8_f32(a.x, a.y, 0, 0);
    lo     = __builtin_amdgcn_cvt_pk_fp8_f32(a.z, a.w, lo, 1);
    int hi = __builtin_amdgcn_cvt_pk_fp8_f32(b.x, b.y, 0, 0);
    hi     = __builtin_amdgcn_cvt_pk_fp8_f32(b.z, b.w, hi, 1);
    *(int2*)(out + i) = make_int2(lo, hi);
}

#define BM 256
#define BN 256
#define BK 128   // one LDS buffer = 2 x K64 halves

// C[m,v] = sum_k A[m,k]*W[v,k]; fused MSE partial per block.
// 256x256 tile, 8 waves (2M x 4N), per-wave 128x64 via 4x2 MFMA 32x32x64 f8f6f4.
// LDS: 2 double-buffers x (2 K64-halves x 16 chunks x 1KB) per operand = 128 KiB.
// Chunk layout / swizzle IDENTICAL to the verified 128^2 kernel (0 bank conflicts):
//   chunk = 16 rows x 64B; stage lane l -> row l>>2, k-quarter (l&3)^f(l>>2),
//   f(r)=(r+(r>>2))&3; fragment read slot = rl*4 + (kq ^ f(rl)).
// Pipeline (catalog T3-minimum): STAGE(t+1) issued BEFORE compute(t); vmcnt(0)
// only AFTER the MFMA cluster (loads land under compute); raw s_barrier (no
// __syncthreads -> no forced vmcnt drain before compute); setprio around MFMA.
__global__ __launch_bounds__(512, 2) void gemm_mse(
    const uint8_t* __restrict__ A8,   // N x H fp8
    const uint8_t* __restrict__ W8,   // V x H fp8
    const float*  __restrict__ target,// N x V
    const float*  __restrict__ bias,  // V
    float* __restrict__ partials)     // one per block
{
    extern __shared__ __align__(16) uint8_t smem[];
    uint8_t* As = smem;            // 2 * 32768
    uint8_t* Bs = smem + 65536;    // 2 * 32768
    __shared__ float red[8];

    const int tid  = threadIdx.x;
    const int w    = tid >> 6;        // wave 0..7
    const int lane = tid & 63;
    const int l32  = lane & 31;
    const int half = lane >> 5;       // k-half within one instruction's K=64
    const int wm   = w >> 2;          // 0..1 : 128-row band
    const int wn   = w & 3;           // 0..3 : 64-col band

    // bijective XCD-aware tile mapping: 64 col-tiles x 16 row-tiles, 1024 % 8 == 0
    const int flat = blockIdx.x;
    const int xcd  = flat & 7;
    const int idx  = flat >> 3;                 // 0..127 per XCD
    const int tx   = xcd * 8 + (idx & 7);       // V tile 0..63
    const int ty   = idx >> 3;                  // N tile 0..15

    const int rowBase = ty * BM;  // N dim
    const int colBase = tx * BN;  // V dim

    f32x16 acc[4][2];
#pragma unroll
    for (int i = 0; i < 4; ++i)
#pragma unroll
        for (int j = 0; j < 2; ++j)
#pragma unroll
            for (int r = 0; r < 16; ++r) acc[i][j][r] = 0.f;

    // ---- staging lane params: 16 rows x 64B per 1KB chunk, swizzled 16B k-quarter
    const int ldrow = lane >> 2;                          // 0..15
    const int ldkq  = (lane & 3) ^ ((ldrow + (ldrow >> 2)) & 3);

    // ---- fragment read offsets (lane-constant), conflict-free swizzled
    const int rl  = lane & 15;
    const int rcb = (lane >> 4) & 1;                      // which 16-row chunk of the 32-row operand
    const int fl  = (rl + (rl >> 2)) & 3;
    int aOff[4][2], bOff[2][2];
#pragma unroll
    for (int i = 0; i < 4; ++i)
#pragma unroll
        for (int c = 0; c < 2; ++c) {
            const int slot = rl * 4 + (((half << 1) + c) ^ fl);
            aOff[i][c] = (wm * 8 + i * 2 + rcb) * 1024 + slot * 16;
        }
#pragma unroll
    for (int j = 0; j < 2; ++j)
#pragma unroll
        for (int c = 0; c < 2; ++c) {
            const int slot = rl * 4 + (((half << 1) + c) ^ fl);
            bOff[j][c] = (wn * 4 + j * 2 + rcb) * 1024 + slot * 16;
        }

    // stage one BK=128 tile: per wave 2 halves x 2 chunks x {A,B} = 8 loads
    auto STAGE = [&](int t, int buf) {
        const int kT = t * BK;
#pragma unroll
        for (int h = 0; h < 2; ++h) {
#pragma unroll
            for (int c = 0; c < 2; ++c) {
                const int cid  = w * 2 + c;               // wave-uniform 0..15
                const int kOff = kT + h * 64 + ldkq * 16;
                const uint8_t* ga = A8 + (size_t)(rowBase + cid * 16 + ldrow) * H_ + kOff;
                __builtin_amdgcn_global_load_lds(
                    (const __attribute__((address_space(1))) void*)ga,
                    (__attribute__((address_space(3))) void*)(As + buf * 32768 + h * 16384 + cid * 1024),
                    16, 0, 0);
                const uint8_t* gb = W8 + (size_t)(colBase + cid * 16 + ldrow) * H_ + kOff;
                __builtin_amdgcn_global_load_lds(
                    (const __attribute__((address_space(1))) void*)gb,
                    (__attribute__((address_space(3))) void*)(Bs + buf * 32768 + h * 16384 + cid * 1024),
                    16, 0, 0);
            }
        }
    };

    // prologue: tile 0
    STAGE(0, 0);
    asm volatile("s_waitcnt vmcnt(0)" ::: "memory");
    __builtin_amdgcn_s_barrier();
    asm volatile("" ::: "memory");

    int cur = 0;
    for (int t = 0; t < 8; ++t) {      // 8 K-tiles of 128
        if (t < 7) STAGE(t + 1, cur ^ 1);   // prefetch overlaps this tile's MFMAs
        const uint8_t* aB = As + cur * 32768;
        const uint8_t* bB = Bs + cur * 32768;
#pragma unroll
        for (int h = 0; h < 2; ++h) {
            i32x8 af[4], bq[2];
#pragma unroll
            for (int i = 0; i < 4; ++i) {
                int4 a0 = *(const int4*)(aB + h * 16384 + aOff[i][0]);
                int4 a1 = *(const int4*)(aB + h * 16384 + aOff[i][1]);
                af[i][0] = a0.x; af[i][1] = a0.y; af[i][2] = a0.z; af[i][3] = a0.w;
                af[i][4] = a1.x; af[i][5] = a1.y; af[i][6] = a1.z; af[i][7] = a1.w;
            }
#pragma unroll
            for (int j = 0; j < 2; ++j) {
                int4 b0 = *(const int4*)(bB + h * 16384 + bOff[j][0]);
                int4 b1 = *(const int4*)(bB + h * 16384 + bOff[j][1]);
                bq[j][0] = b0.x; bq[j][1] = b0.y; bq[j][2] = b0.z; bq[j][3] = b0.w;
                bq[j][4] = b1.x; bq[j][5] = b1.y; bq[j][6] = b1.z; bq[j][7] = b1.w;
            }
            __builtin_amdgcn_s_setprio(1);
#pragma unroll
            for (int i = 0; i < 4; ++i)
#pragma unroll
                for (int j = 0; j < 2; ++j)
                    acc[i][j] = __builtin_amdgcn_mfma_scale_f32_32x32x64_f8f6f4(
                        af[i], bq[j], acc[i][j],
                        0 /*cbsz: fp8 e4m3*/, 0 /*blgp: fp8 e4m3*/,
                        0, 0x7F7F7F7F,   // A scales: 2^0
                        0, 0x7F7F7F7F);  // B scales: 2^0
            __builtin_amdgcn_s_setprio(0);
        }
        // next tile's loads have had the whole compute phase to land -> cheap wait
        if (t < 7) asm volatile("s_waitcnt vmcnt(0)" ::: "memory");
        asm volatile("" ::: "memory");
        __builtin_amdgcn_s_barrier();
        asm volatile("" ::: "memory");
        cur ^= 1;
    }

    // epilogue: 32x32 C/D layout: col = l32, row = (r&3) + 8*(r>>2) + 4*half
    float sum = 0.f;
    float biasj[2];
#pragma unroll
    for (int j = 0; j < 2; ++j) biasj[j] = bias[colBase + wn * 64 + j * 32 + l32];

#pragma unroll
    for (int i = 0; i < 4; ++i) {
#pragma unroll
        for (int r = 0; r < 16; ++r) {
            const int row = (r & 3) + 8 * (r >> 2) + 4 * half;
            const int gm = rowBase + wm * 128 + i * 32 + row;
            const float* trow = target + (size_t)gm * V_ + colBase + wn * 64 + l32;
#pragma unroll
            for (int j = 0; j < 2; ++j) {
                float d = acc[i][j][r] + biasj[j] - trow[j * 32];
                sum += d * d;
            }
        }
    }

    // block reduction (8 waves)
#pragma unroll
    for (int off = 32; off; off >>= 1) sum += __shfl_down(sum, off, 64);
    if (lane == 0) red[w] = sum;
    __syncthreads();
    if (tid == 0) {
        float s = 0.f;
#pragma unroll
        for (int i = 0; i < 8; ++i) s += red[i];
        partials[flat] = s;
    }
}

__global__ void finalize_kernel(const float* __restrict__ partials, float* __restrict__ out, int n) {
    float s = 0.f;
    for (int i = threadIdx.x; i < n; i += 256) s += partials[i];
#pragma unroll
    for (int off = 32; off; off >>= 1) s += __shfl_down(s, off, 64);
    __shared__ float red[4];
    const int w = threadIdx.x >> 6, lane = threadIdx.x & 63;
    if (lane == 0) red[w] = s;
    __syncthreads();
    if (threadIdx.x == 0)
        out[0] = (red[0] + red[1] + red[2] + red[3]) * (1.0f / ((float)N_ * (float)V_));
}

extern "C" void kernel_launch(void* const* d_in, const int* in_sizes, int n_in,
                              void* d_out, int out_size, void* d_ws, size_t ws_size,
                              hipStream_t stream) {
    const float* input  = (const float*)d_in[0];  // N x H
    const float* weight = (const float*)d_in[1];  // V x H
    const float* target = (const float*)d_in[2];  // N x V
    const float* bias   = (const float*)d_in[3];  // V
    float* out = (float*)d_out;

    uint8_t* A8 = (uint8_t*)d_ws;                       // N*H fp8
    uint8_t* W8 = A8 + (size_t)N_ * H_;                 // V*H fp8
    float* partials = (float*)(W8 + (size_t)V_ * H_);   // 1024 floats

    const int nblk0 = (N_ * H_) / (256 * 8);            // 2048
    const int nblk1 = (V_ * H_) / (256 * 8);            // 8192
    cast2_f32_to_fp8<<<nblk0 + nblk1, 256, 0, stream>>>(input, A8, weight, W8, nblk0);

    const int nblocks = (V_ / BN) * (N_ / BM);          // 1024
    gemm_mse<<<nblocks, 512, 131072, stream>>>(A8, W8, target, bias, partials);

    finalize_kernel<<<1, 256, 0, stream>>>(partials, out, nblocks);
}

// Round 2
// 455.436 us; speedup vs baseline: 1.0225x; 1.0225x over previous
//
#include <hip/hip_runtime.h>
#include <hip/hip_bf16.h>
#include <stdint.h>

#define N_ 4096
#define H_ 1024
#define V_ 16384

using i32x8  = __attribute__((ext_vector_type(8))) int;
using f32x16 = __attribute__((ext_vector_type(16))) float;

// 8 floats -> 8 fp8 e4m3 (OCP) per thread; both tensors in one launch
__global__ void cast2_f32_to_fp8(const float* __restrict__ in0, uint8_t* __restrict__ out0,
                                 const float* __restrict__ in1, uint8_t* __restrict__ out1,
                                 int nblk0) {
    const float* in;
    uint8_t* out;
    int bid;
    if (blockIdx.x < (unsigned)nblk0) { in = in0; out = out0; bid = blockIdx.x; }
    else                              { in = in1; out = out1; bid = blockIdx.x - nblk0; }
    size_t i = ((size_t)bid * blockDim.x + threadIdx.x) * 8;
    float4 a = *(const float4*)(in + i);
    float4 b = *(const float4*)(in + i + 4);
    int lo = __builtin_amdgcn_cvt_pk_fp8_f32(a.x, a.y, 0, 0);
    lo     = __builtin_amdgcn_cvt_pk_fp8_f32(a.z, a.w, lo, 1);
    int hi = __builtin_amdgcn_cvt_pk_fp8_f32(b.x, b.y, 0, 0);
    hi     = __builtin_amdgcn_cvt_pk_fp8_f32(b.z, b.w, hi, 1);
    *(int2*)(out + i) = make_int2(lo, hi);
}

#define BM 128
#define BN 128
#define BK 128

// C[m,v] = sum_k A[m,k]*W[v,k]; fused MSE partial per block.
// Verified 128^2 geometry (4 waves, 2 blocks/CU, 0-conflict swizzle) + 2-phase
// deferred-wait pipeline: double-buffered BK=128 LDS (64 KiB), STAGE(t+1)
// issued BEFORE compute(t), vmcnt(0) only AFTER the MFMA cluster, ONE raw
// s_barrier per K-tile (no __syncthreads -> no forced pre-compute drain).
// Target (MSE) values prefetched into VGPRs during K-tiles 6/7 so the
// epilogue's HBM read hides under the last two compute phases.
// LDS chunk layout / swizzle identical to the verified kernel:
//   chunk = 16 rows x 64B; stage lane l -> row l>>2, k-quarter (l&3)^f(l>>2),
//   f(r)=(r+(r>>2))&3; fragment read slot = rl*4 + (kq ^ f(rl)).
__global__ __launch_bounds__(256, 2) void gemm_mse(
    const uint8_t* __restrict__ A8,   // N x H fp8
    const uint8_t* __restrict__ W8,   // V x H fp8
    const float*  __restrict__ target,// N x V
    const float*  __restrict__ bias,  // V
    float* __restrict__ partials)     // one per block
{
    extern __shared__ __align__(16) uint8_t smem[];
    uint8_t* As = smem;            // 2 buf x 16KB
    uint8_t* Bs = smem + 32768;    // 2 buf x 16KB
    __shared__ float red[4];

    const int tid  = threadIdx.x;
    const int w    = tid >> 6;        // wave 0..3
    const int lane = tid & 63;
    const int l32  = lane & 31;
    const int half = lane >> 5;       // k-half within one instruction's K=64
    const int wm   = w >> 1;          // 2x2 wave grid, 64x64 each
    const int wn   = w & 1;

    // XCD-aware tile mapping: 128 col-tiles x 32 row-tiles (4096 % 8 == 0)
    const int flat = blockIdx.x;
    const int xcd  = flat & 7;
    const int idx  = flat >> 3;                 // 0..511 per XCD
    const int tx   = xcd * 16 + (idx & 15);     // V tile 0..127
    const int ty   = idx >> 4;                  // N tile 0..31

    const int rowBase = ty * BM;  // N dim
    const int colBase = tx * BN;  // V dim

    f32x16 acc[2][2];
#pragma unroll
    for (int i = 0; i < 2; ++i)
#pragma unroll
        for (int j = 0; j < 2; ++j)
#pragma unroll
            for (int r = 0; r < 16; ++r) acc[i][j][r] = 0.f;

    // ---- staging lane params: 16 rows x 64B per 1KB chunk, swizzled 16B k-quarter
    const int ldrow = lane >> 2;                          // 0..15
    const int ldkq  = (lane & 3) ^ ((ldrow + (ldrow >> 2)) & 3);

    // ---- fragment read offsets (lane-constant), conflict-free swizzled
    const int rl  = lane & 15;
    const int rcb = (lane >> 4) & 1;                      // which 16-row chunk
    const int fl  = (rl + (rl >> 2)) & 3;
    int aOff[2][2], bOff[2][2];
#pragma unroll
    for (int i = 0; i < 2; ++i)
#pragma unroll
        for (int c = 0; c < 2; ++c) {
            const int slot = rl * 4 + (((half << 1) + c) ^ fl);
            aOff[i][c] = ((wm * 2 + i) * 2 + rcb) * 1024 + slot * 16;
            bOff[i][c] = ((wn * 2 + i) * 2 + rcb) * 1024 + slot * 16;
        }

    // bias loaded BEFORE the loop so no stray VMEM ops interleave the pipeline
    float biasj[2];
#pragma unroll
    for (int j = 0; j < 2; ++j) biasj[j] = bias[colBase + wn * 64 + j * 32 + l32];

    // stage one BK=128 tile into buffer buf: per wave 2 halves x 2 chunks x {A,B}
    auto STAGE = [&](int t, int buf) {
        const int kT = t * BK;
#pragma unroll
        for (int h = 0; h < 2; ++h) {
#pragma unroll
            for (int c = 0; c < 2; ++c) {
                const int cid  = w * 2 + c;               // wave-uniform 0..7
                const int kOff = kT + h * 64 + ldkq * 16;
                const uint8_t* ga = A8 + (size_t)(rowBase + cid * 16 + ldrow) * H_ + kOff;
                __builtin_amdgcn_global_load_lds(
                    (const __attribute__((address_space(1))) void*)ga,
                    (__attribute__((address_space(3))) void*)(As + buf * 16384 + h * 8192 + cid * 1024),
                    16, 0, 0);
                const uint8_t* gb = W8 + (size_t)(colBase + cid * 16 + ldrow) * H_ + kOff;
                __builtin_amdgcn_global_load_lds(
                    (const __attribute__((address_space(1))) void*)gb,
                    (__attribute__((address_space(3))) void*)(Bs + buf * 16384 + h * 8192 + cid * 1024),
                    16, 0, 0);
            }
        }
    };

    float tgt0[16][2], tgt1[16][2];   // target prefetch (static indexing only)

    // prologue: tile 0
    STAGE(0, 0);
    asm volatile("s_waitcnt vmcnt(0)" ::: "memory");
    __builtin_amdgcn_s_barrier();
    asm volatile("" ::: "memory");

    int cur = 0;
    for (int t = 0; t < 8; ++t) {      // 8 K-tiles of 128
        if (t < 7) STAGE(t + 1, cur ^ 1);   // prefetch overlaps this tile's MFMAs
        asm volatile("" ::: "memory");      // keep tgt issues AFTER stage issues
        if (t == 6) {
#pragma unroll
            for (int r = 0; r < 16; ++r) {
                const int row = (r & 3) + 8 * (r >> 2) + 4 * half;
                const float* trow = target + (size_t)(rowBase + wm * 64 + 0 * 32 + row) * V_
                                    + colBase + wn * 64 + l32;
                tgt0[r][0] = trow[0];
                tgt0[r][1] = trow[32];
            }
        }
        if (t == 7) {
#pragma unroll
            for (int r = 0; r < 16; ++r) {
                const int row = (r & 3) + 8 * (r >> 2) + 4 * half;
                const float* trow = target + (size_t)(rowBase + wm * 64 + 1 * 32 + row) * V_
                                    + colBase + wn * 64 + l32;
                tgt1[r][0] = trow[0];
                tgt1[r][1] = trow[32];
            }
        }

        const uint8_t* aB = As + cur * 16384;
        const uint8_t* bB = Bs + cur * 16384;
#pragma unroll
        for (int h = 0; h < 2; ++h) {
            i32x8 af[2], bq[2];
#pragma unroll
            for (int i = 0; i < 2; ++i) {
                int4 a0 = *(const int4*)(aB + h * 8192 + aOff[i][0]);
                int4 a1 = *(const int4*)(aB + h * 8192 + aOff[i][1]);
                af[i][0] = a0.x; af[i][1] = a0.y; af[i][2] = a0.z; af[i][3] = a0.w;
                af[i][4] = a1.x; af[i][5] = a1.y; af[i][6] = a1.z; af[i][7] = a1.w;
                int4 b0 = *(const int4*)(bB + h * 8192 + bOff[i][0]);
                int4 b1 = *(const int4*)(bB + h * 8192 + bOff[i][1]);
                bq[i][0] = b0.x; bq[i][1] = b0.y; bq[i][2] = b0.z; bq[i][3] = b0.w;
                bq[i][4] = b1.x; bq[i][5] = b1.y; bq[i][6] = b1.z; bq[i][7] = b1.w;
            }
            __builtin_amdgcn_s_setprio(1);
#pragma unroll
            for (int i = 0; i < 2; ++i)
#pragma unroll
                for (int j = 0; j < 2; ++j)
                    acc[i][j] = __builtin_amdgcn_mfma_scale_f32_32x32x64_f8f6f4(
                        af[i], bq[j], acc[i][j],
                        0 /*cbsz: fp8 e4m3*/, 0 /*blgp: fp8 e4m3*/,
                        0, 0x7F7F7F7F,   // A scales: 2^0
                        0, 0x7F7F7F7F);  // B scales: 2^0
            __builtin_amdgcn_s_setprio(0);
        }

        if (t < 7) {
            // stage loads for t+1 have had the whole compute phase to land
            asm volatile("s_waitcnt vmcnt(0)" ::: "memory");
            __builtin_amdgcn_s_barrier();
            asm volatile("" ::: "memory");
        }
        cur ^= 1;
    }

    // epilogue: 32x32 C/D layout: col = l32, row = (r&3) + 8*(r>>2) + 4*half
    // tgt0 consumed first so the wait on tgt1 overlaps the i=0 FMA chain.
    float sum = 0.f;
#pragma unroll
    for (int r = 0; r < 16; ++r) {
#pragma unroll
        for (int j = 0; j < 2; ++j) {
            float d = acc[0][j][r] + biasj[j] - tgt0[r][j];
            sum += d * d;
        }
    }
#pragma unroll
    for (int r = 0; r < 16; ++r) {
#pragma unroll
        for (int j = 0; j < 2; ++j) {
            float d = acc[1][j][r] + biasj[j] - tgt1[r][j];
            sum += d * d;
        }
    }

    // block reduction
#pragma unroll
    for (int off = 32; off; off >>= 1) sum += __shfl_down(sum, off, 64);
    if (lane == 0) red[w] = sum;
    __syncthreads();
    if (tid == 0)
        partials[flat] = red[0] + red[1] + red[2] + red[3];
}

__global__ void finalize_kernel(const float* __restrict__ partials, float* __restrict__ out, int n) {
    float s = 0.f;
    for (int i = threadIdx.x; i < n; i += 256) s += partials[i];
#pragma unroll
    for (int off = 32; off; off >>= 1) s += __shfl_down(s, off, 64);
    __shared__ float red[4];
    const int w = threadIdx.x >> 6, lane = threadIdx.x & 63;
    if (lane == 0) red[w] = s;
    __syncthreads();
    if (threadIdx.x == 0)
        out[0] = (red[0] + red[1] + red[2] + red[3]) * (1.0f / ((float)N_ * (float)V_));
}

extern "C" void kernel_launch(void* const* d_in, const int* in_sizes, int n_in,
                              void* d_out, int out_size, void* d_ws, size_t ws_size,
                              hipStream_t stream) {
    const float* input  = (const float*)d_in[0];  // N x H
    const float* weight = (const float*)d_in[1];  // V x H
    const float* target = (const float*)d_in[2];  // N x V
    const float* bias   = (const float*)d_in[3];  // V
    float* out = (float*)d_out;

    uint8_t* A8 = (uint8_t*)d_ws;                       // N*H fp8
    uint8_t* W8 = A8 + (size_t)N_ * H_;                 // V*H fp8
    float* partials = (float*)(W8 + (size_t)V_ * H_);   // 4096 floats

    const int nblk0 = (N_ * H_) / (256 * 8);            // 2048
    const int nblk1 = (V_ * H_) / (256 * 8);            // 8192
    cast2_f32_to_fp8<<<nblk0 + nblk1, 256, 0, stream>>>(input, A8, weight, W8, nblk0);

    const int nblocks = (V_ / BN) * (N_ / BM);          // 4096
    gemm_mse<<<nblocks, 256, 65536, stream>>>(A8, W8, target, bias, partials);

    finalize_kernel<<<1, 256, 0, stream>>>(partials, out, nblocks);
}